// Round 12
// baseline (280.204 us; speedup 1.0000x reference)
//
#include <hip/hip_runtime.h>

typedef float  f32x4  __attribute__((ext_vector_type(4)));
typedef float  f32x16 __attribute__((ext_vector_type(16)));
typedef int    i32x4  __attribute__((ext_vector_type(4)));
typedef int    i32x8  __attribute__((ext_vector_type(8)));

#define AS1 __attribute__((address_space(1)))
#define AS3 __attribute__((address_space(3)))

// ---- software float -> OCP e4m3fn (RNE), valid for |x| <= 448 ----
__device__ __forceinline__ unsigned int f2e4m3(float x){
    union{float f; unsigned u;} v; v.f = x;
    unsigned s = (v.u >> 24) & 0x80u;
    float ax = fabsf(x);
    if (ax > 448.0f) ax = 448.0f;
    if (ax < 0.015625f){
        int d = (int)__builtin_rintf(ax * 512.0f);
        return s | (unsigned)d;
    }
    v.f = ax;
    unsigned u = v.u + 0x7ffffu + ((v.u >> 20) & 1u);
    unsigned E = (u >> 23) - 120u;
    unsigned M = (u >> 20) & 7u;
    return s | (E << 3) | M;
}

// ---- 4 floats -> packed 4x e4m3 (HW cvt if available) ----
__device__ __forceinline__ unsigned int pk4(float x0, float x1, float x2, float x3){
#if __has_builtin(__builtin_amdgcn_cvt_pk_fp8_f32)
    int u = __builtin_amdgcn_cvt_pk_fp8_f32(x0, x1, 0, false);
    u     = __builtin_amdgcn_cvt_pk_fp8_f32(x2, x3, u, true);
    return (unsigned)u;
#else
    return f2e4m3(x0) | (f2e4m3(x1) << 8) | (f2e4m3(x2) << 16) | (f2e4m3(x3) << 24);
#endif
}

__device__ __forceinline__ void gload16(const unsigned char* g, const char* l){
    __builtin_amdgcn_global_load_lds((const AS1 void*)g, (AS3 void*)l, 16, 0, 0);
}

__device__ __forceinline__ i32x8 ld_frag(const char* p0, const char* p1){
    i32x4 lo = *(const i32x4*)p0;
    i32x4 hi = *(const i32x4*)p1;
    return __builtin_shufflevector(lo, hi, 0,1,2,3,4,5,6,7);
}

#define GBAR() do{ asm volatile("" ::: "memory"); __builtin_amdgcn_s_barrier(); \
                   asm volatile("" ::: "memory"); }while(0)
#define VMW(N)  asm volatile("s_waitcnt vmcnt(" #N ")" ::: "memory")

// ---------------------------------------------------------------------------
// Row l2-normalize [rows][1024] f32 -> fp8 e4m3 *16 (MX scale 2^-4), row-major.
// ---------------------------------------------------------------------------
__global__ __launch_bounds__(256) void norm_rows_fp8(const float* __restrict__ in,
                                                     unsigned int* __restrict__ out){
    const int row = blockIdx.x;
    const int t   = threadIdx.x;
    f32x4 x = ((const f32x4*)(in + (size_t)row * 1024))[t];
    float ss = x[0]*x[0] + x[1]*x[1] + x[2]*x[2] + x[3]*x[3];
    #pragma unroll
    for (int o = 32; o > 0; o >>= 1) ss += __shfl_xor(ss, o);
    __shared__ float red[4];
    if ((t & 63) == 0) red[t >> 6] = ss;
    __syncthreads();
    float tot = red[0] + red[1] + red[2] + red[3];
    float inv = 16.0f / fmaxf(sqrtf(tot), 1e-12f);
    out[(size_t)row * 256 + t] = pk4(x[0]*inv, x[1]*inv, x[2]*inv, x[3]*inv);
}

// ---------------------------------------------------------------------------
// Final in-place row l2-normalize of d_out [N][1024] f32.
// ---------------------------------------------------------------------------
__global__ __launch_bounds__(256) void norm_rows_f32(float* __restrict__ buf){
    const int row = blockIdx.x;
    const int t   = threadIdx.x;
    f32x4* p = (f32x4*)(buf + (size_t)row * 1024);
    f32x4 x = p[t];
    float ss = x[0]*x[0] + x[1]*x[1] + x[2]*x[2] + x[3]*x[3];
    #pragma unroll
    for (int o = 32; o > 0; o >>= 1) ss += __shfl_xor(ss, o);
    __shared__ float red[4];
    if ((t & 63) == 0) red[t >> 6] = ss;
    __syncthreads();
    float tot = red[0] + red[1] + red[2] + red[3];
    float inv = 1.0f / fmaxf(sqrtf(tot), 1e-12f);
    p[t] = x * inv;
}

// ---------------------------------------------------------------------------
// offset [C=2048][D=1024] f32 -> offt [D][C] fp8 e4m3 *64 (2^-6), row-major,
// fused sum(offset^2) -> atomicAdd(reg_out). Tile: 64(c) x 64(d).
// ---------------------------------------------------------------------------
__global__ __launch_bounds__(256) void transpose_off(const float* __restrict__ off,
                                                     unsigned char* __restrict__ offt,
                                                     float* __restrict__ reg_out){
    __shared__ unsigned char t_lds[64][68];
    const int t  = threadIdx.x;
    const int c0 = blockIdx.x * 64;
    const int d0 = blockIdx.y * 64;
    float ss = 0.f;
    #pragma unroll
    for (int p = 0; p < 4; ++p){
        int c  = p * 16 + (t >> 4);
        int dq = t & 15;
        f32x4 v = *(const f32x4*)(off + (size_t)(c0 + c) * 1024 + d0 + dq * 4);
        ss += v[0]*v[0] + v[1]*v[1] + v[2]*v[2] + v[3]*v[3];
        unsigned u = pk4(v[0]*64.0f, v[1]*64.0f, v[2]*64.0f, v[3]*64.0f);
        #pragma unroll
        for (int j = 0; j < 4; ++j) t_lds[dq * 4 + j][c] = (unsigned char)(u >> (8*j));
    }
    __syncthreads();
    #pragma unroll
    for (int p = 0; p < 4; ++p){
        int d  = p * 16 + (t >> 4);
        int cq = t & 15;
        unsigned int o = *(const unsigned int*)&t_lds[d][cq * 4];
        *(unsigned int*)(offt + (size_t)(d0 + d) * 2048 + c0 + cq * 4) = o;
    }
    #pragma unroll
    for (int o = 32; o > 0; o >>= 1) ss += __shfl_xor(ss, o);
    __shared__ float red[4];
    if ((t & 63) == 0) red[t >> 6] = ss;
    __syncthreads();
    if (t == 0) atomicAdd(reg_out, red[0] + red[1] + red[2] + red[3]);
}

// ---------------------------------------------------------------------------
// FP8 GEMM, m201-template port: acc = 2^(SA-127)*2^(SB-127) * sum A[m,k]B[n,k]
// (A,B fp8 e4m3 row-major, lda/ldb BYTES.)
// 256x256 tile, 512 threads (8 waves 2Mx4N, wave tile 128x64, acc[4][2]x16).
// BK=128 B/iter; dbuf 2x64KB = 128 KiB; buffer = 16KB quarters
// [Ak0|Ak1|Bk0|Bk1] (256 rows x 64B, granule swizzle g^=(row>>1)&3 via
// pre-swizzled global source). 4 phases/iter:
//   P: {ds_reads | stage 1 quarter(t+1)} -> midbar -> setprio(1)+4 MFMA
//      +setprio(0) -> [vmcnt(4) at P1,P3] -> endbar
// NO lgkm walls: builtin mfma_scale -> compiler-counted lgkmcnt, so waves
// whose reads finish early MFMA while others drain (the 8-phase overlap).
// FIFO ledger (2 loads/quarter/thread, order Ak0,Bk0,Ak1,Bk1): vmcnt(4)
// twice/iter, never 0 in steady state; quarters land >=2 phases before use.
// EPI==1: Wout = e4m3(exp(10*acc-10)*1024)  (ldw bytes)
// EPI==2: Fout = Cadd + acc                  (ldo floats)
// ---------------------------------------------------------------------------
template<int EPI, int SA, int SB>
__global__ __launch_bounds__(512, 2)
void gemm8p(const unsigned char* __restrict__ A, int lda,
            const unsigned char* __restrict__ B, int ldb,
            int K,
            unsigned char* __restrict__ Wout, int ldw,
            const float* __restrict__ Cadd, float* __restrict__ Fout, int ldo)
{
    extern __shared__ char smem[];             // 2 x 64 KiB
    const int tid  = threadIdx.x;

    // ---- XCD-aware bijective remap ----
    int bx = blockIdx.x, by = blockIdx.y;
    {
        const int gx = gridDim.x, gy = gridDim.y;
        const int nwg = gx * gy;
        if ((nwg & 7) == 0){
            const int lid = bx + gx * by;
            const int q   = nwg >> 3;
            const int n   = (lid & 7) * q + (lid >> 3);
            const int sh  = 31 - __clz(gy);    // gy is a power of two
            bx = n >> sh;
            by = n & (gy - 1);
        }
    }
    const int m0   = bx * 256;
    const int n0   = by * 256;
    const int wid  = tid >> 6, lane = tid & 63;
    const int wr   = wid >> 2, wc = wid & 3;   // 2x4 waves, wave tile 128x64
    const int l31  = lane & 31, hg = lane >> 5;

    // ---- staging: quarter = 256 rows x 64B = 16KB = 2 passes of 8KB
    // (512 thr x 16B). phys granule (tid&3) at row tid>>2 holds logical
    // (tid&3)^((row>>1)&3) -> pre-swizzled source; +128 rows preserves XOR.
    const int srow = tid >> 2;                 // 0..127
    const int sg   = (tid & 3) ^ ((tid >> 3) & 3);
    const unsigned char* sA = A + (size_t)(m0 + srow) * lda + sg * 16;
    const unsigned char* sB = B + (size_t)(n0 + srow) * ldb + sg * 16;
    const int lp = tid * 16;

    // quarters: Ak0 @0, Ak1 @16384, Bk0 @32768, Bk1 @49152
    auto stgA = [&](char* wb, int kq, int ke){
        gload16(sA + kq * 64 + ke,                      wb + kq * 16384 + lp);
        gload16(sA + (size_t)128 * lda + kq * 64 + ke,  wb + kq * 16384 + 8192 + lp);
    };
    auto stgB = [&](char* wb, int kq, int ke){
        gload16(sB + kq * 64 + ke,                      wb + 32768 + kq * 16384 + lp);
        gload16(sB + (size_t)128 * ldb + kq * 64 + ke,  wb + 32768 + kq * 16384 + 8192 + lp);
    };

    // ---- frag read offsets (quarter-relative, swizzled): lane row=base+l31,
    // 32 k-bytes = 2 b128 at granules (2hg+j)^((row>>1)&3).
    int aoff[4][2], boff[2][2];
    #pragma unroll
    for (int m = 0; m < 4; ++m){
        int row = wr * 128 + m * 32 + l31;
        int sw  = (row >> 1) & 3;
        aoff[m][0] = row * 64 + (((hg << 1) | 0) ^ sw) * 16;
        aoff[m][1] = row * 64 + (((hg << 1) | 1) ^ sw) * 16;
    }
    #pragma unroll
    for (int n = 0; n < 2; ++n){
        int row = wc * 64 + n * 32 + l31;
        int sw  = (row >> 1) & 3;
        boff[n][0] = row * 64 + (((hg << 1) | 0) ^ sw) * 16;
        boff[n][1] = row * 64 + (((hg << 1) | 1) ^ sw) * 16;
    }

    f32x16 acc[4][2] = {};
    const int nsteps = K >> 7;                 // BK = 128 bytes/iter (>= 2)

#define RD_A2(dst, q, mb) { \
    dst[0] = ld_frag((q) + aoff[(mb)][0],   (q) + aoff[(mb)][1]); \
    dst[1] = ld_frag((q) + aoff[(mb)+1][0], (q) + aoff[(mb)+1][1]); }
#define RD_B2(q) { \
    fb[0] = ld_frag((q) + boff[0][0], (q) + boff[0][1]); \
    fb[1] = ld_frag((q) + boff[1][0], (q) + boff[1][1]); }
#define MFMA4(mb, av) { __builtin_amdgcn_s_setprio(1); \
    _Pragma("unroll") for (int mi = 0; mi < 2; ++mi) \
    _Pragma("unroll") for (int ni = 0; ni < 2; ++ni) \
        acc[(mb)+mi][ni] = __builtin_amdgcn_mfma_scale_f32_32x32x64_f8f6f4( \
            av[mi], fb[ni], acc[(mb)+mi][ni], 0, 0, 0, SA, 0, SB); \
    __builtin_amdgcn_s_setprio(0); }

    i32x8 fa01[2], fa23[2], fb[2];

    // ---- prologue: stage iter0 (Ak0,Bk0,Ak1,Bk1 = 8 loads);
    //      vmcnt(4): Ak0,Bk0 landed, Ak1,Bk1 in flight ----
    stgA(smem, 0, 0); stgB(smem, 0, 0);
    stgA(smem, 1, 0); stgB(smem, 1, 0);
    VMW(4);
    GBAR();

    #pragma unroll 1
    for (int t = 0; t < nsteps - 1; ++t){
        const char* rb = smem + (t & 1) * 65536;
        char*       wb = smem + ((t + 1) & 1) * 65536;
        const int   ke = (t + 1) * 128;
        // P0: reads k0 {A0,A1,B}; stage Ak0(t+1)
        RD_A2(fa01, rb, 0); RD_B2(rb + 32768);
        stgA(wb, 0, ke);
        GBAR();
        MFMA4(0, fa01);
        GBAR();
        // P1: reads k0 {A2,A3}; stage Bk0(t+1); vmcnt: Ak1,Bk1(t) landed
        RD_A2(fa23, rb, 2);
        stgB(wb, 0, ke);
        GBAR();
        MFMA4(2, fa23);
        VMW(4);
        GBAR();
        // P2: reads k1 {A0,A1,B}; stage Ak1(t+1)
        RD_A2(fa01, rb + 16384, 0); RD_B2(rb + 49152);
        stgA(wb, 1, ke);
        GBAR();
        MFMA4(0, fa01);
        GBAR();
        // P3: reads k1 {A2,A3}; stage Bk1(t+1); vmcnt: Ak0,Bk0(t+1) landed
        RD_A2(fa23, rb + 16384, 2);
        stgB(wb, 1, ke);
        GBAR();
        MFMA4(2, fa23);
        VMW(4);
        GBAR();
    }
    {   // ---- last iter: no staging; drain Ak1,Bk1(last) at P1 ----
        const char* rb = smem + ((nsteps - 1) & 1) * 65536;
        RD_A2(fa01, rb, 0); RD_B2(rb + 32768);
        GBAR();
        MFMA4(0, fa01);
        GBAR();
        RD_A2(fa23, rb, 2);
        GBAR();
        MFMA4(2, fa23);
        VMW(0);
        GBAR();
        RD_A2(fa01, rb + 16384, 0); RD_B2(rb + 49152);
        GBAR();
        MFMA4(0, fa01);
        GBAR();
        RD_A2(fa23, rb + 16384, 2);
        GBAR();
        MFMA4(2, fa23);
    }
#undef RD_A2
#undef RD_B2
#undef MFMA4

    asm volatile("s_nop 7\n\ts_nop 7");

    // C/D layout (32x32): col = lane&31, row = (r&3) + 8*(r>>2) + 4*(lane>>5)
    #pragma unroll
    for (int m = 0; m < 4; ++m){
        #pragma unroll
        for (int n = 0; n < 2; ++n){
            const int grb = m0 + wr * 128 + m * 32;
            const int gc  = n0 + wc * 64  + n * 32 + l31;
            if (EPI == 1){
                #pragma unroll
                for (int q = 0; q < 4; ++q){
                    const int row0 = grb + 8 * q + 4 * hg;
                    float w0 = exp2f(fmaf(14.4269504f, acc[m][n][4*q+0], -4.4269504f));
                    float w1 = exp2f(fmaf(14.4269504f, acc[m][n][4*q+1], -4.4269504f));
                    float w2 = exp2f(fmaf(14.4269504f, acc[m][n][4*q+2], -4.4269504f));
                    float w3 = exp2f(fmaf(14.4269504f, acc[m][n][4*q+3], -4.4269504f));
                    unsigned u = pk4(w0, w1, w2, w3);
                    unsigned char* p = Wout + (size_t)row0 * ldw + gc;
                    p[0]                = (unsigned char)u;
                    p[(size_t)ldw]      = (unsigned char)(u >> 8);
                    p[(size_t)ldw * 2]  = (unsigned char)(u >> 16);
                    p[(size_t)ldw * 3]  = (unsigned char)(u >> 24);
                }
            } else {
                #pragma unroll
                for (int r = 0; r < 16; ++r){
                    const int row = (r & 3) + 8 * (r >> 2) + 4 * hg;
                    Fout[(size_t)(grb + row) * ldo + gc] =
                        Cadd[(size_t)(grb + row) * ldo + gc] + acc[m][n][r];
                }
            }
        }
    }
}

// ---------------------------------------------------------------------------
extern "C" void kernel_launch(void* const* d_in, const int* in_sizes, int n_in,
                              void* d_out, int out_size, void* d_ws, size_t ws_size,
                              hipStream_t stream)
{
    (void)n_in; (void)out_size;
    const float* inp = (const float*)d_in[0];
    const float* pos = (const float*)d_in[1];
    const float* off = (const float*)d_in[2];
    float* out = (float*)d_out;

    const int D = 1024, C = 2048;
    const int N = in_sizes[0] / D;            // 32768

    // workspace (bytes): b_fp8[C*D] | offt[D*C] | a_fp8[Mc*D] | w_buf[Mc*C]
    unsigned char* b_fp8 = (unsigned char*)d_ws;
    unsigned char* offt  = b_fp8 + (size_t)C * D;
    unsigned char* a_fp8 = offt + (size_t)D * C;
    size_t fixed = (size_t)C * D * 2;
    size_t avail = ws_size > fixed ? ws_size - fixed : 0;
    int Mc = 256;
    for (int cand = N; cand >= 256; cand >>= 1){
        if ((size_t)cand * (size_t)(D + C) <= avail){ Mc = cand; break; }
    }
    if (Mc > N) Mc = N;
    unsigned char* w_buf = a_fp8 + (size_t)Mc * D;

    // scales (e8m0, 2^(b-127)): GEMM1 a,pos *16 -> 123,123;
    // GEMM2 W *1024 -> 117, offt *64 -> 121.
    hipFuncSetAttribute(reinterpret_cast<const void*>(&gemm8p<1,123,123>),
                        hipFuncAttributeMaxDynamicSharedMemorySize, 131072);
    hipFuncSetAttribute(reinterpret_cast<const void*>(&gemm8p<2,117,121>),
                        hipFuncAttributeMaxDynamicSharedMemorySize, 131072);

    float* reg_out = out + (size_t)N * D;
    hipMemsetAsync(reg_out, 0, sizeof(float), stream);

    transpose_off<<<dim3(C / 64, D / 64), 256, 0, stream>>>(off, offt, reg_out);
    norm_rows_fp8<<<C, 256, 0, stream>>>(pos, (unsigned int*)b_fp8);

    for (int r0 = 0; r0 < N; r0 += Mc){
        norm_rows_fp8<<<Mc, 256, 0, stream>>>(inp + (size_t)r0 * D, (unsigned int*)a_fp8);
        // GEMM1: W[Mc][C] = e4m3(1024 * exp(10*(a.b^T) - 10))
        gemm8p<1,123,123><<<dim3(Mc / 256, C / 256), 512, 131072, stream>>>(
            a_fp8, D, b_fp8, D, D, w_buf, C, nullptr, nullptr, 0);
        // GEMM2: out[Mc][D] = inp + (2^-16 scaled) W . offt^T
        gemm8p<2,117,121><<<dim3(Mc / 256, D / 256), 512, 131072, stream>>>(
            w_buf, C, offt, C, C, nullptr, 0, inp + (size_t)r0 * D, out + (size_t)r0 * D, D);
    }
    norm_rows_f32<<<N, 256, 0, stream>>>(out);
}